// Round 18
// baseline (1823.349 us; speedup 1.0000x reference)
//
#include <hip/hip_runtime.h>

// ---------------- problem constants ----------------
#define T_SEQ 80
#define NB    5120
#define NBH   (NB * 256)
#define NVOC  100

// ---------------- ws layout (bytes), total ~17.7 MB ----------------
#define OFF_TABLE0 0u          // 100*1024*4 = 409600 (f32, np-packed)
#define OFF_BIAS1  409600u     // 1024*4     = 4096
#define OFF_BPACK  413696u     // 786432*2   = 1572864 (bf16 frag-layout weights)
#define OFF_RING0  1986560u    // 2 slots bf16 [5120][256] FRAGMENT-MAJOR = 5242880
#define OFF_RING1  7229440u    // 2 slots bf16             = 5242880
#define OFF_C0     12472320u   // _Float16, c4 layout      = 2621440
#define OFF_C1     15093760u   // _Float16, c4 layout      = 2621440

typedef float  f32x4  __attribute__((ext_vector_type(4)));
typedef __bf16 bf16x8 __attribute__((ext_vector_type(8)));
typedef _Float16 f16x4 __attribute__((ext_vector_type(4)));
typedef unsigned short u16x8 __attribute__((ext_vector_type(8)));

// Fragment-major ring layout (shorts):
//   gr -> mi=gr/160, rowin=gr%160, wm=rowin/80, m=(rowin%80)/16, l15r=rowin%16
//   col -> kc=col>>5, lhi=(col&31)>>3, i=col&7
//   P = mi*40960 + kc*5120 + wm*2560 + m*512 + l15r*32 + lhi*8 + i

// column permutation: np -> original gate-major row (i,f,g,o blocks of 256)
__device__ __forceinline__ int colmap(int np) {
  int gate = (np >> 4) & 3;
  int j    = ((np >> 6) << 4) | (np & 15);
  return gate * 256 + j;
}

__device__ __forceinline__ unsigned short f2bf(float f) {
  unsigned int u = __float_as_uint(f);
  u += 0x7fffu + ((u >> 16) & 1u);   // RNE
  return (unsigned short)(u >> 16);
}
__device__ __forceinline__ float bf2f(unsigned short s) {
  return __uint_as_float(((unsigned int)s) << 16);
}
__device__ __forceinline__ float sigm(float x) {
  x = fminf(fmaxf(x, -20.f), 20.f);
  return 1.f / (1.f + __expf(-x));
}
__device__ __forceinline__ float tanh_(float x) {
  x = fminf(fmaxf(x, -10.f), 10.f);
  float e = __expf(2.f * x);
  return (e - 1.f) / (e + 1.f);
}

// ---------------- prep: table + bias + bf16 weight pack + zero out ----------------
__global__ void prep_kernel(const float* __restrict__ emb,
                            const float* __restrict__ w_ih0, const float* __restrict__ w_hh0,
                            const float* __restrict__ b_ih0, const float* __restrict__ b_hh0,
                            const float* __restrict__ w_ih1, const float* __restrict__ w_hh1,
                            const float* __restrict__ b_ih1, const float* __restrict__ b_hh1,
                            float* __restrict__ table0, float* __restrict__ bias1,
                            unsigned short* __restrict__ Bpack,
                            float* __restrict__ out, int out_size) {
  int idx = blockIdx.x * 256 + threadIdx.x;
  if (idx < out_size) out[idx] = 0.f;     // replaces hipMemsetAsync dispatch
  if (idx < 102400) {
    int v = idx >> 10, np = idx & 1023;
    int row = colmap(np);
    float s = b_ih0[row] + b_hh0[row];
#pragma unroll
    for (int e = 0; e < 8; ++e) s = fmaf(emb[v * 8 + e], w_ih0[row * 8 + e], s);
    table0[idx] = s;
  } else if (idx < 103424) {
    int np = idx - 102400;
    bias1[np] = b_ih1[colmap(np)] + b_hh1[colmap(np)];
  } else {
    int i2 = idx - 103424;               // < 786432
    int i    = i2 & 7;
    int t    = (i2 >> 3) & 511;
    int ni   = (i2 >> 12) & 7;
    int slot = i2 >> 15;                 // 0..23
    int np   = ni * 128 + ((t >> 6) << 4) + (t & 15);
    int row  = colmap(np);
    int k    = (((t & 63) >> 4) << 3) + i;
    float val;
    if (slot < 8) {
      val = w_hh0[row * 256 + slot * 32 + k];
    } else {
      int kc = slot - 8;
      const float* W = (kc < 8) ? w_ih1 : w_hh1;
      val = W[row * 256 + (kc & 7) * 32 + k];
    }
    Bpack[i2] = f2bf(val);
  }
}

// ---------------- per-step kernel: fragment-major rings, depth-3 register ring -------
// Grid 512: p -> (xcd=p&7, idx=p>>3). idx<32: L0(t=s); else L1(t=s-1).
// Tile [160 x 128], 256 thr = 4 waves (2m x 2n), wave [80 x 64].
// A and B load DIRECTLY global->VGPR (3-deep, 2-ahead), zero LDS in K-loop,
// zero barriers in K-loop (one barrier for xs before epilogue).
__global__ __launch_bounds__(256, 2) void step_kernel(
    int s, const int* __restrict__ x,
    const float* __restrict__ table0, const float* __restrict__ bias1,
    const unsigned short* __restrict__ Bpack,
    unsigned short* __restrict__ ring0, unsigned short* __restrict__ ring1,
    _Float16* __restrict__ c0h, _Float16* __restrict__ c1h) {
  __shared__ int xs[160];

  const int tid = threadIdx.x;
  const int lane = tid & 63, wid = tid >> 6;
  const int l15 = lane & 15, lhi = lane >> 4;
  const int wm = wid >> 1, wn = wid & 1, rw = wm * 80;

  const int p = blockIdx.x;
  const int xcd = p & 7, idx = p >> 3;
  const bool isL0 = idx < 32;
  const int sub = idx & 31;
  const int mi = xcd * 4 + (sub >> 3);
  const int ni = sub & 7;
  const int rows = mi * 160;

  int t;
  if (isL0) { if (s == T_SEQ) return; t = s; }
  else      { if (s == 0)     return; t = s - 1; }

  const unsigned short* ring0Prev = ring0 + ((s + 1) & 1) * NBH;  // h0(s-1)
  unsigned short*       ring0Cur  = ring0 + (s & 1) * NBH;        // h0(s)
  const unsigned short* h1Prev    = ring1 + (s & 1) * NBH;        // h1(s-2)
  unsigned short*       h1Cur     = ring1 + ((s + 1) & 1) * NBH;  // h1(s-1)

  const int KC = isL0 ? (t > 0 ? 8 : 0) : (t > 0 ? 16 : 8);
  const int slotBase = isL0 ? 0 : 8;
  const int jh = (ni * 2 + wn) * 16 + l15;          // h-column

  // stage x tile (L0 only); published by the barrier after the K-loop
  if (isL0 && tid < 160) xs[tid] = x[t * NB + rows + tid];

  // HOIST: epilogue's cold loads issued now; complete under the GEMM.
  _Float16* ch = isL0 ? c0h : c1h;
  f16x4 cold[5];
#pragma unroll
  for (int m = 0; m < 5; ++m) cold[m] = (f16x4)(_Float16)0.f;
  if (t > 0) {
#pragma unroll
    for (int m = 0; m < 5; ++m) {
      const int cbase = ((rows + rw + m * 16) >> 2) + lhi;
      cold[m] = *(const f16x4*)(ch + cbase * 1024 + jh * 4);
    }
  }
  float b0 = 0.f, b1 = 0.f, b2 = 0.f, b3 = 0.f;
  if (!isL0) {
    const int bbb = ni * 128 + wn * 64 + l15;
    b0 = bias1[bbb]; b1 = bias1[bbb + 16]; b2 = bias1[bbb + 32]; b3 = bias1[bbb + 48];
  }

  // per-lane fragment base pointers (shorts)
  const int laneoff = (lane & 15) * 32 + (lane >> 4) * 8;
  const unsigned short* apR = ring0Prev + mi * 40960 + wm * 2560 + laneoff;
  const unsigned short* apH = h1Prev    + mi * 40960 + wm * 2560 + laneoff;
  const unsigned short* bp  = Bpack + ((size_t)(slotBase * 8 + ni) * 512 + wn * 256 + lane) * 8;

  f32x4 acc[5][4];
#pragma unroll
  for (int m = 0; m < 5; ++m)
#pragma unroll
    for (int nf = 0; nf < 4; ++nf) acc[m][nf] = (f32x4)0.f;

  bf16x8 Ar[3][5], Br[3][4];   // depth-3 register ring (2-ahead)

#define LOADG(sl_, kc_) do { \
    const unsigned short* _Ab = (isL0 || (kc_) < 8) ? apR : apH; \
    const int _ko = ((kc_) & 7) * 5120; \
    _Pragma("unroll") \
    for (int _m = 0; _m < 5; ++_m) \
      Ar[sl_][_m] = *(const bf16x8*)(_Ab + _ko + _m * 512); \
    const unsigned short* _Bb = bp + (size_t)(kc_) * 32768; \
    _Pragma("unroll") \
    for (int _nf = 0; _nf < 4; ++_nf) \
      Br[sl_][_nf] = *(const bf16x8*)(_Bb + _nf * 512); \
  } while (0)

#define MFMAG(sl_) do { \
    _Pragma("unroll") \
    for (int _nf = 0; _nf < 4; ++_nf) \
      _Pragma("unroll") \
      for (int _m = 0; _m < 5; ++_m) \
        acc[_m][_nf] = __builtin_amdgcn_mfma_f32_16x16x32_bf16(Ar[sl_][_m], Br[sl_][_nf], acc[_m][_nf], 0, 0, 0); \
  } while (0)

  if (isL0) {
    if (t > 0) {
      LOADG(0, 0); LOADG(1, 1);
#pragma unroll
      for (int kc = 0; kc < 8; ++kc) {
        if (kc + 2 < 8) LOADG((kc + 2) % 3, kc + 2);
        MFMAG(kc % 3);
      }
    }
  } else if (t > 0) {
    LOADG(0, 0); LOADG(1, 1);
#pragma unroll
    for (int kc = 0; kc < 16; ++kc) {
      if (kc + 2 < 16) LOADG((kc + 2) % 3, kc + 2);
      MFMAG(kc % 3);
    }
  } else {
    LOADG(0, 0); LOADG(1, 1);
#pragma unroll
    for (int kc = 0; kc < 8; ++kc) {
      if (kc + 2 < 8) LOADG((kc + 2) % 3, kc + 2);
      MFMAG(kc % 3);
    }
  }

  __syncthreads();   // publish xs (L0); harmless for L1

  // ---------------- epilogue: LSTM cell update ----------------
  // fragment-major write base: kc=ni, col-rem = wn*16+l15 -> lhi_c*8+i = wn*16+l15
  unsigned short* wring = (isL0 ? ring0Cur : h1Cur)
      + mi * 40960 + ni * 5120 + wm * 2560 + lhi * 128 + wn * 16 + l15;
  if (isL0) {
    const int tbb = ni * 128 + wn * 64 + l15;
#pragma unroll
    for (int m = 0; m < 5; ++m) {
      const int cbase = ((rows + rw + m * 16) >> 2) + lhi;   // c4 row-group
      f16x4 cnew;
#pragma unroll
      for (int r = 0; r < 4; ++r) {
        int rowl = rw + m * 16 + lhi * 4 + r;
        const float* tb = table0 + xs[rowl] * 1024 + tbb;
        float gi = acc[m][0][r] + tb[0];
        float gf = acc[m][1][r] + tb[16];
        float gg = acc[m][2][r] + tb[32];
        float go = acc[m][3][r] + tb[48];
        float cn = sigm(gf) * (float)cold[m][r] + sigm(gi) * tanh_(gg);
        cnew[r] = (_Float16)cn;
        wring[m * 512 + r * 32] = f2bf(sigm(go) * tanh_(cn));
      }
      *(f16x4*)(c0h + cbase * 1024 + jh * 4) = cnew;
    }
  } else {
#pragma unroll
    for (int m = 0; m < 5; ++m) {
      const int cbase = ((rows + rw + m * 16) >> 2) + lhi;
      f16x4 cnew;
#pragma unroll
      for (int r = 0; r < 4; ++r) {
        float gi = acc[m][0][r] + b0;
        float gf = acc[m][1][r] + b1;
        float gg = acc[m][2][r] + b2;
        float go = acc[m][3][r] + b3;
        float cn = sigm(gf) * (float)cold[m][r] + sigm(gi) * tanh_(gg);
        cnew[r] = (_Float16)cn;
        wring[m * 512 + r * 32] = f2bf(sigm(go) * tanh_(cn));
      }
      *(f16x4*)(c1h + cbase * 1024 + jh * 4) = cnew;
    }
  }
#undef LOADG
#undef MFMAG
}

// ---------------- decoder: 128 blocks = 8 q-windows x 16 row-quads ----------------
// Stages fragment-major h1 rows into LDS (8x64B chunks per row), then the
// proven wave-per-v coalesced dec_w dot.
__global__ __launch_bounds__(256) void decoder_kernel(
    const unsigned short* __restrict__ h1, const float* __restrict__ dec_w,
    const float* __restrict__ dec_b, float* __restrict__ out) {
  __shared__ float hs[4][2560];
  const int tid = threadIdx.x, lane = tid & 63, wid = tid >> 6;
  const int b = blockIdx.x;
  const int win = b & 7;
  const int rt  = b >> 3;            // 0..15
  const int qoff = win * 2560;

  // gather: 320 chunks of 64B (rr 4 x rowloc 10 x kc 8)
  for (int c = tid; c < 320; c += 256) {
    int rr = c / 80;
    int rowloc = (c % 80) / 8;
    int kc = c & 7;
    int gr = (rt * 4 + rr) * 80 + win * 10 + rowloc;
    int mi = gr / 160, rowin = gr % 160;
    int wm = rowin / 80, m = (rowin % 80) / 16, l15r = rowin & 15;
    const unsigned short* src = h1 + mi * 40960 + kc * 5120 + wm * 2560 + m * 512 + l15r * 32;
    float* dst = &hs[rr][rowloc * 256 + kc * 32];
#pragma unroll
    for (int e = 0; e < 32; e += 8) {
      u16x8 v8 = *(const u16x8*)(src + e);
#pragma unroll
      for (int j = 0; j < 8; ++j) dst[e + j] = bf2f(v8[j]);
    }
  }
  __syncthreads();

  for (int vv = wid; vv < NVOC; vv += 4) {
    const float* wp = dec_w + (size_t)vv * 20480 + qoff + lane * 4;
    float s0 = 0.f, s1 = 0.f, s2 = 0.f, s3 = 0.f;
#pragma unroll
    for (int it = 0; it < 10; ++it) {
      f32x4 w4 = *(const f32x4*)(wp + it * 256);
      const int qq = it * 256 + lane * 4;
      f32x4 h0 = *(const f32x4*)&hs[0][qq];
      f32x4 h1v = *(const f32x4*)&hs[1][qq];
      f32x4 h2 = *(const f32x4*)&hs[2][qq];
      f32x4 h3 = *(const f32x4*)&hs[3][qq];
#pragma unroll
      for (int e = 0; e < 4; ++e) {
        s0 = fmaf(w4[e], h0[e], s0);
        s1 = fmaf(w4[e], h1v[e], s1);
        s2 = fmaf(w4[e], h2[e], s2);
        s3 = fmaf(w4[e], h3[e], s3);
      }
    }
#pragma unroll
    for (int off = 32; off > 0; off >>= 1) {
      s0 += __shfl_down(s0, off, 64);
      s1 += __shfl_down(s1, off, 64);
      s2 += __shfl_down(s2, off, 64);
      s3 += __shfl_down(s3, off, 64);
    }
    if (lane == 0) {
      float bias = (win == 0) ? dec_b[vv] : 0.f;
      atomicAdd(&out[(rt * 4 + 0) * 100 + vv], s0 + bias);
      atomicAdd(&out[(rt * 4 + 1) * 100 + vv], s1 + bias);
      atomicAdd(&out[(rt * 4 + 2) * 100 + vv], s2 + bias);
      atomicAdd(&out[(rt * 4 + 3) * 100 + vv], s3 + bias);
    }
  }
}

// ---------------- host launch: prep + 81 step kernels + decoder ----------------
extern "C" void kernel_launch(void* const* d_in, const int* in_sizes, int n_in,
                              void* d_out, int out_size, void* d_ws, size_t ws_size,
                              hipStream_t stream) {
  const int*   x     = (const int*)d_in[0];
  const float* emb   = (const float*)d_in[1];
  const float* w_ih0 = (const float*)d_in[2];
  const float* w_hh0 = (const float*)d_in[3];
  const float* b_ih0 = (const float*)d_in[4];
  const float* b_hh0 = (const float*)d_in[5];
  const float* w_ih1 = (const float*)d_in[6];
  const float* w_hh1 = (const float*)d_in[7];
  const float* b_ih1 = (const float*)d_in[8];
  const float* b_hh1 = (const float*)d_in[9];
  const float* dec_w = (const float*)d_in[10];
  const float* dec_b = (const float*)d_in[11];
  float* out = (float*)d_out;
  char* ws = (char*)d_ws;

  float*          table0 = (float*)(ws + OFF_TABLE0);
  float*          bias1  = (float*)(ws + OFF_BIAS1);
  unsigned short* Bpack  = (unsigned short*)(ws + OFF_BPACK);
  unsigned short* ring0  = (unsigned short*)(ws + OFF_RING0);
  unsigned short* ring1  = (unsigned short*)(ws + OFF_RING1);
  _Float16*       c0h    = (_Float16*)(ws + OFF_C0);
  _Float16*       c1h    = (_Float16*)(ws + OFF_C1);

  prep_kernel<<<3476, 256, 0, stream>>>(emb, w_ih0, w_hh0, b_ih0, b_hh0,
                                        w_ih1, w_hh1, b_ih1, b_hh1,
                                        table0, bias1, Bpack, out, out_size);
  for (int s = 0; s <= T_SEQ; ++s)
    step_kernel<<<512, 256, 0, stream>>>(s, x, table0, bias1, Bpack,
                                         ring0, ring1, c0h, c1h);
  decoder_kernel<<<128, 256, 0, stream>>>(ring1 + NBH, dec_w, dec_b, out);
}

// Round 19
// 1474.425 us; speedup vs baseline: 1.2367x; 1.2367x over previous
//
#include <hip/hip_runtime.h>

// ---------------- problem constants ----------------
#define T_SEQ 80
#define NB    5120
#define NBH   (NB * 256)
#define NVOC  100

// ---------------- ws layout (bytes), total ~17.7 MB ----------------
#define OFF_TABLE0 0u          // 100*1024*4 = 409600 (f32, np-packed)
#define OFF_BIAS1  409600u     // 1024*4     = 4096
#define OFF_BPACK  413696u     // 786432*2   = 1572864 (bf16 frag-layout weights)
#define OFF_RING0  1986560u    // 2 slots bf16 [5120][256] = 5242880
#define OFF_RING1  7229440u    // 2 slots bf16             = 5242880
#define OFF_C0     12472320u   // _Float16, c4 layout      = 2621440
#define OFF_C1     15093760u   // _Float16, c4 layout      = 2621440

// LDS: Ab 2x(160x80B)=25600 + Bb 2x8192=16384 + xs 640
#define SMEM_BYTES 42624

typedef float  f32x4  __attribute__((ext_vector_type(4)));
typedef __bf16 bf16x8 __attribute__((ext_vector_type(8)));
typedef short  s16x8  __attribute__((ext_vector_type(8)));
typedef _Float16 f16x4 __attribute__((ext_vector_type(4)));
typedef unsigned short u16x8 __attribute__((ext_vector_type(8)));

// column permutation: np -> original gate-major row (i,f,g,o blocks of 256)
__device__ __forceinline__ int colmap(int np) {
  int gate = (np >> 4) & 3;
  int j    = ((np >> 6) << 4) | (np & 15);
  return gate * 256 + j;
}

__device__ __forceinline__ unsigned short f2bf(float f) {
  unsigned int u = __float_as_uint(f);
  u += 0x7fffu + ((u >> 16) & 1u);   // RNE
  return (unsigned short)(u >> 16);
}
__device__ __forceinline__ float bf2f(unsigned short s) {
  return __uint_as_float(((unsigned int)s) << 16);
}
__device__ __forceinline__ float sigm(float x) {
  x = fminf(fmaxf(x, -20.f), 20.f);
  return 1.f / (1.f + __expf(-x));
}
__device__ __forceinline__ float tanh_(float x) {
  x = fminf(fmaxf(x, -10.f), 10.f);
  float e = __expf(2.f * x);
  return (e - 1.f) / (e + 1.f);
}

// ---------------- prep: table + bias + bf16 weight pack + zero out ----------------
__global__ void prep_kernel(const float* __restrict__ emb,
                            const float* __restrict__ w_ih0, const float* __restrict__ w_hh0,
                            const float* __restrict__ b_ih0, const float* __restrict__ b_hh0,
                            const float* __restrict__ w_ih1, const float* __restrict__ w_hh1,
                            const float* __restrict__ b_ih1, const float* __restrict__ b_hh1,
                            float* __restrict__ table0, float* __restrict__ bias1,
                            unsigned short* __restrict__ Bpack,
                            float* __restrict__ out, int out_size) {
  int idx = blockIdx.x * 256 + threadIdx.x;
  if (idx < out_size) out[idx] = 0.f;     // replaces hipMemsetAsync dispatch
  if (idx < 102400) {
    int v = idx >> 10, np = idx & 1023;
    int row = colmap(np);
    float s = b_ih0[row] + b_hh0[row];
#pragma unroll
    for (int e = 0; e < 8; ++e) s = fmaf(emb[v * 8 + e], w_ih0[row * 8 + e], s);
    table0[idx] = s;
  } else if (idx < 103424) {
    int np = idx - 102400;
    bias1[np] = b_ih1[colmap(np)] + b_hh1[colmap(np)];
  } else {
    int i2 = idx - 103424;               // < 786432
    int i    = i2 & 7;
    int t    = (i2 >> 3) & 511;
    int ni   = (i2 >> 12) & 7;
    int slot = i2 >> 15;                 // 0..23
    int np   = ni * 128 + ((t >> 6) << 4) + (t & 15);
    int row  = colmap(np);
    int k    = (((t & 63) >> 4) << 3) + i;
    float val;
    if (slot < 8) {
      val = w_hh0[row * 256 + slot * 32 + k];
    } else {
      int kc = slot - 8;
      const float* W = (kc < 8) ? w_ih1 : w_hh1;
      val = W[row * 256 + (kc & 7) * 32 + k];
    }
    Bpack[i2] = f2bf(val);
  }
}

// ---------------- per-step kernel (R17 structure, verbatim) ----------------
// Grid 512: p -> (xcd=p&7, idx=p>>3). idx<32: L0(t=s); else L1(t=s-1).
// Tile [160 x 128], 256 thr = 4 waves (2m x 2n), wave [80 x 64].
__global__ __launch_bounds__(256, 1) void step_kernel(
    int s, const int* __restrict__ x,
    const float* __restrict__ table0, const float* __restrict__ bias1,
    const unsigned short* __restrict__ Bpack,
    unsigned short* __restrict__ ring0, unsigned short* __restrict__ ring1,
    _Float16* __restrict__ c0h, _Float16* __restrict__ c1h) {
  extern __shared__ char smem[];
  char* Ab = smem;            // [2][160*80]
  char* Bb = smem + 25600;    // [2][512*16]
  int*  xs = (int*)(smem + 41984);   // [160]

  const int tid = threadIdx.x;
  const int lane = tid & 63, wid = tid >> 6;
  const int l15 = lane & 15, lhi = lane >> 4;
  const int wm = wid >> 1, wn = wid & 1, rw = wm * 80;

  const int p = blockIdx.x;
  const int xcd = p & 7, idx = p >> 3;
  const bool isL0 = idx < 32;
  const int sub = idx & 31;
  const int mi = xcd * 4 + (sub >> 3);
  const int ni = sub & 7;
  const int rows = mi * 160;

  int t;
  if (isL0) { if (s == T_SEQ) return; t = s; }
  else      { if (s == 0)     return; t = s - 1; }

  const unsigned short* ring0Prev = ring0 + ((s + 1) & 1) * NBH;  // h0(s-1)
  unsigned short*       ring0Cur  = ring0 + (s & 1) * NBH;        // h0(s)
  const unsigned short* h1Prev    = ring1 + (s & 1) * NBH;        // h1(s-2)
  unsigned short*       h1Cur     = ring1 + ((s + 1) & 1) * NBH;  // h1(s-1)

  const int KC = isL0 ? (t > 0 ? 8 : 0) : (t > 0 ? 16 : 8);
  const int jh = (ni * 2 + wn) * 16 + l15;          // h-column

  // stage x tile (L0 only): coalesced, consumed by epilogue via LDS broadcast
  if (isL0 && tid < 160) xs[tid] = x[t * NB + rows + tid];

  // HOIST: issue epilogue's cold loads now; they complete under the GEMM.
  _Float16* ch = isL0 ? c0h : c1h;
  f16x4 cold[5];
#pragma unroll
  for (int m = 0; m < 5; ++m) cold[m] = (f16x4)(_Float16)0.f;
  if (t > 0) {
#pragma unroll
    for (int m = 0; m < 5; ++m) {
      const int cbase = ((rows + rw + m * 16) >> 2) + lhi;
      cold[m] = *(const f16x4*)(ch + cbase * 1024 + jh * 4);
    }
  }
  float b0 = 0.f, b1 = 0.f, b2 = 0.f, b3 = 0.f;
  if (!isL0) {
    const int bbb = ni * 128 + wn * 64 + l15;
    b0 = bias1[bbb]; b1 = bias1[bbb + 16]; b2 = bias1[bbb + 32]; b3 = bias1[bbb + 48];
  }

  f32x4 acc[5][4];
#pragma unroll
  for (int m = 0; m < 5; ++m)
#pragma unroll
    for (int nf = 0; nf < 4; ++nf) acc[m][nf] = (f32x4)0.f;

  uint4 au0, au1, au2;
  s16x8 bsr0, bsr1;

#define LOADR(kc_) do { \
    const unsigned short* _As; int _ko; \
    if (isL0) { _As = ring0Prev; _ko = (kc_) * 32; } \
    else { _As = ((kc_) < 8) ? ring0Prev : h1Prev; _ko = ((kc_) & 7) * 32; } \
    { int _c = tid;       au0 = *(const uint4*)(_As + (rows + (_c >> 2)) * 256 + _ko + ((_c & 3) << 3)); } \
    { int _c = tid + 256; au1 = *(const uint4*)(_As + (rows + (_c >> 2)) * 256 + _ko + ((_c & 3) << 3)); } \
    if (tid < 128) { int _c = tid + 512; au2 = *(const uint4*)(_As + (rows + (_c >> 2)) * 256 + _ko + ((_c & 3) << 3)); } \
    int _slot = isL0 ? (kc_) : (8 + (kc_)); \
    bsr0 = *(const s16x8*)(Bpack + (((_slot * 8 + ni) * 512 + tid) << 3)); \
    bsr1 = *(const s16x8*)(Bpack + (((_slot * 8 + ni) * 512 + tid + 256) << 3)); \
  } while (0)

#define STORER(buf_) do { \
    char* _ab = Ab + (buf_) * 12800; \
    *(uint4*)(_ab + (tid >> 2) * 80 + (tid & 3) * 16) = au0; \
    { int _c = tid + 256; *(uint4*)(_ab + (_c >> 2) * 80 + (_c & 3) * 16) = au1; } \
    if (tid < 128) { int _c = tid + 512; *(uint4*)(_ab + (_c >> 2) * 80 + (_c & 3) * 16) = au2; } \
    char* _bb = Bb + (buf_) * 8192; \
    *(s16x8*)(_bb + tid * 16) = bsr0; \
    *(s16x8*)(_bb + (tid + 256) * 16) = bsr1; \
  } while (0)

#define CONSUME(buf_) do { \
    const char* _ab = Ab + (buf_) * 12800; \
    const char* _bp = Bb + (buf_) * 8192; \
    bf16x8 _bld[4]; \
    _Pragma("unroll") \
    for (int _nf = 0; _nf < 4; ++_nf) \
      _bld[_nf] = *(const bf16x8*)(_bp + ((wn * 4 + _nf) * 64 + lane) * 16); \
    _Pragma("unroll") \
    for (int _m = 0; _m < 5; ++_m) { \
      bf16x8 _a = *(const bf16x8*)(_ab + (rw + _m * 16 + l15) * 80 + lhi * 16); \
      _Pragma("unroll") \
      for (int _nf = 0; _nf < 4; ++_nf) \
        acc[_m][_nf] = __builtin_amdgcn_mfma_f32_16x16x32_bf16(_a, _bld[_nf], acc[_m][_nf], 0, 0, 0); \
    } \
  } while (0)

  if (KC > 0) { LOADR(0); STORER(0); }
#pragma unroll 1
  for (int kc = 0; kc < KC; ++kc) {
    __syncthreads();                       // publishes buf[kc&1] (+ xs on kc==0)
    const bool more = (kc + 1 < KC);
    if (more) LOADR(kc + 1);               // issue early: hides under MFMAs
    CONSUME(kc & 1);
    if (more) STORER((kc + 1) & 1);        // write late (readers synced at top)
  }
  if (KC == 0) __syncthreads();            // publish xs (s==0 L0 path)

  // ---------------- epilogue: LSTM cell update ----------------
  if (isL0) {
    const int tbb = ni * 128 + wn * 64 + l15;
#pragma unroll
    for (int m = 0; m < 5; ++m) {
      const int cbase = ((rows + rw + m * 16) >> 2) + lhi;   // c4 row-group
      f16x4 cnew;
#pragma unroll
      for (int r = 0; r < 4; ++r) {
        int rowl = rw + m * 16 + lhi * 4 + r;
        const float* tb = table0 + xs[rowl] * 1024 + tbb;
        float gi = acc[m][0][r] + tb[0];
        float gf = acc[m][1][r] + tb[16];
        float gg = acc[m][2][r] + tb[32];
        float go = acc[m][3][r] + tb[48];
        float cn = sigm(gf) * (float)cold[m][r] + sigm(gi) * tanh_(gg);
        cnew[r] = (_Float16)cn;
        ring0Cur[(rows + rowl) * 256 + jh] = f2bf(sigm(go) * tanh_(cn));
      }
      *(f16x4*)(c0h + cbase * 1024 + jh * 4) = cnew;
    }
  } else {
#pragma unroll
    for (int m = 0; m < 5; ++m) {
      const int cbase = ((rows + rw + m * 16) >> 2) + lhi;
      f16x4 cnew;
#pragma unroll
      for (int r = 0; r < 4; ++r) {
        int rowl = rw + m * 16 + lhi * 4 + r;
        float gi = acc[m][0][r] + b0;
        float gf = acc[m][1][r] + b1;
        float gg = acc[m][2][r] + b2;
        float go = acc[m][3][r] + b3;
        float cn = sigm(gf) * (float)cold[m][r] + sigm(gi) * tanh_(gg);
        cnew[r] = (_Float16)cn;
        h1Cur[(rows + rowl) * 256 + jh] = f2bf(sigm(go) * tanh_(cn));
      }
      *(f16x4*)(c1h + cbase * 1024 + jh * 4) = cnew;
    }
  }
#undef LOADR
#undef STORER
#undef CONSUME
}

// ---------------- decoder v3: 256 blocks = 16 q-windows x 16 row-quads ------------
// Window = 1280 floats; b%8 == win%8 -> all 16 blocks of a window on one XCD
// (512KB dec_w slice L2-resident). Shorter per-v chain (5 f32x4 loads).
__global__ __launch_bounds__(256) void decoder_kernel(
    const unsigned short* __restrict__ h1, const float* __restrict__ dec_w,
    const float* __restrict__ dec_b, float* __restrict__ out) {
  __shared__ float hs[4][1280];
  const int tid = threadIdx.x, lane = tid & 63, wid = tid >> 6;
  const int b = blockIdx.x;
  const int win = b & 15;
  const int rt  = b >> 4;            // 0..15
  const int qoff = win * 1280;

#pragma unroll
  for (int rr = 0; rr < 4; ++rr) {
    const unsigned short* src = h1 + (size_t)(rt * 4 + rr) * 20480 + qoff;
    if (tid < 160) {
      u16x8 v8 = *(const u16x8*)(src + tid * 8);
#pragma unroll
      for (int e = 0; e < 8; ++e) hs[rr][tid * 8 + e] = bf2f(v8[e]);
    }
  }
  __syncthreads();

  for (int vv = wid; vv < NVOC; vv += 4) {
    const float* wp = dec_w + (size_t)vv * 20480 + qoff + lane * 4;
    float s0 = 0.f, s1 = 0.f, s2 = 0.f, s3 = 0.f;
#pragma unroll
    for (int it = 0; it < 5; ++it) {
      f32x4 w4 = *(const f32x4*)(wp + it * 256);
      const int qq = it * 256 + lane * 4;
      f32x4 h0 = *(const f32x4*)&hs[0][qq];
      f32x4 h1v = *(const f32x4*)&hs[1][qq];
      f32x4 h2 = *(const f32x4*)&hs[2][qq];
      f32x4 h3 = *(const f32x4*)&hs[3][qq];
#pragma unroll
      for (int e = 0; e < 4; ++e) {
        s0 = fmaf(w4[e], h0[e], s0);
        s1 = fmaf(w4[e], h1v[e], s1);
        s2 = fmaf(w4[e], h2[e], s2);
        s3 = fmaf(w4[e], h3[e], s3);
      }
    }
#pragma unroll
    for (int off = 32; off > 0; off >>= 1) {
      s0 += __shfl_down(s0, off, 64);
      s1 += __shfl_down(s1, off, 64);
      s2 += __shfl_down(s2, off, 64);
      s3 += __shfl_down(s3, off, 64);
    }
    if (lane == 0) {
      float bias = (win == 0) ? dec_b[vv] : 0.f;
      atomicAdd(&out[(rt * 4 + 0) * 100 + vv], s0 + bias);
      atomicAdd(&out[(rt * 4 + 1) * 100 + vv], s1 + bias);
      atomicAdd(&out[(rt * 4 + 2) * 100 + vv], s2 + bias);
      atomicAdd(&out[(rt * 4 + 3) * 100 + vv], s3 + bias);
    }
  }
}

// ---------------- host launch: prep + 81 step kernels + decoder ----------------
extern "C" void kernel_launch(void* const* d_in, const int* in_sizes, int n_in,
                              void* d_out, int out_size, void* d_ws, size_t ws_size,
                              hipStream_t stream) {
  const int*   x     = (const int*)d_in[0];
  const float* emb   = (const float*)d_in[1];
  const float* w_ih0 = (const float*)d_in[2];
  const float* w_hh0 = (const float*)d_in[3];
  const float* b_ih0 = (const float*)d_in[4];
  const float* b_hh0 = (const float*)d_in[5];
  const float* w_ih1 = (const float*)d_in[6];
  const float* w_hh1 = (const float*)d_in[7];
  const float* b_ih1 = (const float*)d_in[8];
  const float* b_hh1 = (const float*)d_in[9];
  const float* dec_w = (const float*)d_in[10];
  const float* dec_b = (const float*)d_in[11];
  float* out = (float*)d_out;
  char* ws = (char*)d_ws;

  float*          table0 = (float*)(ws + OFF_TABLE0);
  float*          bias1  = (float*)(ws + OFF_BIAS1);
  unsigned short* Bpack  = (unsigned short*)(ws + OFF_BPACK);
  unsigned short* ring0  = (unsigned short*)(ws + OFF_RING0);
  unsigned short* ring1  = (unsigned short*)(ws + OFF_RING1);
  _Float16*       c0h    = (_Float16*)(ws + OFF_C0);
  _Float16*       c1h    = (_Float16*)(ws + OFF_C1);

  prep_kernel<<<3476, 256, 0, stream>>>(emb, w_ih0, w_hh0, b_ih0, b_hh0,
                                        w_ih1, w_hh1, b_ih1, b_hh1,
                                        table0, bias1, Bpack, out, out_size);
  hipFuncSetAttribute((const void*)step_kernel,
                      hipFuncAttributeMaxDynamicSharedMemorySize, SMEM_BYTES);
  for (int s = 0; s <= T_SEQ; ++s)
    step_kernel<<<512, 256, SMEM_BYTES, stream>>>(s, x, table0, bias1, Bpack,
                                                  ring0, ring1, c0h, c1h);
  decoder_kernel<<<256, 256, 0, stream>>>(ring1 + NBH, dec_w, dec_b, out);
}